// Round 9
// baseline (50.074 us; speedup 1.0000x reference)
//
#include <hip/hip_runtime.h>
#include <hip/hip_bf16.h>
#include <hip/hip_cooperative_groups.h>

namespace cg = cooperative_groups;

typedef __attribute__((ext_vector_type(4))) float f32x4;
typedef __attribute__((ext_vector_type(4))) double f64x4;
typedef __attribute__((ext_vector_type(8))) short short8;

#define NA 1024
#define NB 1024
#define KF 256
#define DIM 128
#define GRID 256

// Fused cooperative: Phase A (proj via f64 MFMA, probe-decoded D layout) ->
// cg::this_grid().sync() -> Phase B (out = P @ M^T via bf16 MFMA).
// Grid = 256 = 1 block/CU. Runtime-managed grid barrier replaces the hand-rolled
// atomic protocol that cost ~20us in R7/R8 (agent-scope cache-op storm).

union SharedU {
    struct { float Xs[32][132]; float Fs[64][132]; } pa;   // 50.7 KB
    struct { short LA[64][264]; short LB[64][264]; } pb;   // 67.6 KB
};

__global__ __launch_bounds__(256) void fused_kernel(
    const float* __restrict__ a, const float* __restrict__ b,
    const float* __restrict__ feats,
    __hip_bfloat16* __restrict__ P, __hip_bfloat16* __restrict__ M,
    float* __restrict__ out)
{
    __shared__ SharedU sh;
    const int t = threadIdx.x;
    const int bb = blockIdx.x;

    // ================= Phase A: fk = X @ feats^T -> P(relu), M(mask<=0) =========
    {
        const int rb = bb >> 2;            // 0..63: 32-row group of concat [a;b]
        const int cb = bb & 3;             // 0..3 : 64-col group of fk
        const int row0 = rb * 32;
        const int col0 = cb * 64;
        const bool isA = row0 < NA;
        const float* __restrict__ src = isA ? a : b;
        const int r0 = isA ? row0 : row0 - NA;

        // stage X: 32 rows x 32 f32x4 chunks = 1024, 4/thread (coalesced)
#pragma unroll
        for (int i = 0; i < 4; ++i) {
            int idx = t + i * 256;
            int r = idx >> 5, c4 = idx & 31;
            *(f32x4*)&sh.pa.Xs[r][c4 * 4] =
                *(const f32x4*)(src + (size_t)(r0 + r) * DIM + c4 * 4);
        }
        // stage F: 64 rows x 32 chunks = 2048, 8/thread
#pragma unroll
        for (int i = 0; i < 8; ++i) {
            int idx = t + i * 256;
            int r = idx >> 5, c4 = idx & 31;
            *(f32x4*)&sh.pa.Fs[r][c4 * 4] =
                *(const f32x4*)(feats + (size_t)(col0 + r) * DIM + c4 * 4);
        }
        __syncthreads();

        const int l = t & 63, w = t >> 6;
        const int fr = l & 15, fq = l >> 4;

        // layout probe: probe[r] = 4*m + 256*n for this lane's acc slot r
        f64x4 probe = {0.0, 0.0, 0.0, 0.0};
        probe = __builtin_amdgcn_mfma_f64_16x16x4f64((double)fr, 1.0, probe, 0, 0, 0);
        probe = __builtin_amdgcn_mfma_f64_16x16x4f64(1.0, 64.0 * (double)fr, probe, 0, 0, 0);

        // wave w: rows [16*(w&1), +16), cols [32*(w>>1), +32) as 2 16-col tiles
        const int wrow = (w & 1) * 16;
        const int wcol = (w >> 1) * 32;
        const float* __restrict__ xr  = &sh.pa.Xs[wrow + fr][fq];
        const float* __restrict__ fp0 = &sh.pa.Fs[wcol + fr][fq];
        const float* __restrict__ fp1 = &sh.pa.Fs[wcol + 16 + fr][fq];

        // 4 independent chains: 2 tiles x 2 parities (covers f64 MFMA latency)
        f64x4 acc[2][2] = {{{0.,0.,0.,0.},{0.,0.,0.,0.}},{{0.,0.,0.,0.},{0.,0.,0.,0.}}};
#pragma unroll
        for (int s = 0; s < 32; s += 2) {
            double x0 = (double)xr[s * 4],     x1 = (double)xr[s * 4 + 4];
            double f00 = (double)fp0[s * 4],   f01 = (double)fp0[s * 4 + 4];
            double f10 = (double)fp1[s * 4],   f11 = (double)fp1[s * 4 + 4];
            acc[0][0] = __builtin_amdgcn_mfma_f64_16x16x4f64(x0, f00, acc[0][0], 0, 0, 0);
            acc[1][0] = __builtin_amdgcn_mfma_f64_16x16x4f64(x0, f10, acc[1][0], 0, 0, 0);
            acc[0][1] = __builtin_amdgcn_mfma_f64_16x16x4f64(x1, f01, acc[0][1], 0, 0, 0);
            acc[1][1] = __builtin_amdgcn_mfma_f64_16x16x4f64(x1, f11, acc[1][1], 0, 0, 0);
        }

#pragma unroll
        for (int tt = 0; tt < 2; ++tt) {
#pragma unroll
            for (int r = 0; r < 4; ++r) {
                int code = (int)probe[r];
                int m = (code >> 2) & 15;
                int n = code >> 8;
                double v = acc[tt][0][r] + acc[tt][1][r];
                size_t off = (size_t)(r0 + wrow + m) * KF + col0 + wcol + tt * 16 + n;
                if (isA) {
                    float vr = (v > 0.0) ? (float)v : 0.0f;
                    P[off] = __float2bfloat16(vr);
                } else {
                    float vr = (v <= 0.0) ? 1.0f : 0.0f;
                    M[off] = __float2bfloat16(vr);
                }
            }
        }
    }

    // ================= grid-wide barrier (runtime-managed) ======================
    cg::this_grid().sync();

    // ================= Phase B: out = P @ M^T ===================================
    {
        const int row0 = (bb >> 4) * 64;
        const int col0 = (bb & 15) * 64;
        const short* Pa = (const short*)P;
        const short* Mb = (const short*)M;

#pragma unroll
        for (int i = 0; i < 8; ++i) {
            int c = t + i * 256;
            int row = c >> 5;
            int c8 = (c & 31) << 3;
            *(short8*)&sh.pb.LA[row][c8] = *(const short8*)(Pa + (size_t)(row0 + row) * KF + c8);
            *(short8*)&sh.pb.LB[row][c8] = *(const short8*)(Mb + (size_t)(col0 + row) * KF + c8);
        }
        __syncthreads();

        const int lane = t & 63;
        const int wid = t >> 6;
        const int wr = (wid >> 1) * 32;
        const int wc = (wid & 1) * 32;
        const int fr = lane & 15;
        const int fq = lane >> 4;

        f32x4 acc[2][2];
#pragma unroll
        for (int m = 0; m < 2; ++m)
#pragma unroll
            for (int n = 0; n < 2; ++n)
                acc[m][n] = (f32x4){0.f, 0.f, 0.f, 0.f};

#pragma unroll
        for (int kk = 0; kk < KF / 32; ++kk) {
            const int kb = kk * 32 + fq * 8;
            short8 a0 = *(const short8*)&sh.pb.LA[wr + fr][kb];
            short8 a1 = *(const short8*)&sh.pb.LA[wr + 16 + fr][kb];
            short8 b0 = *(const short8*)&sh.pb.LB[wc + fr][kb];
            short8 b1 = *(const short8*)&sh.pb.LB[wc + 16 + fr][kb];
            acc[0][0] = __builtin_amdgcn_mfma_f32_16x16x32_bf16(a0, b0, acc[0][0], 0, 0, 0);
            acc[0][1] = __builtin_amdgcn_mfma_f32_16x16x32_bf16(a0, b1, acc[0][1], 0, 0, 0);
            acc[1][0] = __builtin_amdgcn_mfma_f32_16x16x32_bf16(a1, b0, acc[1][0], 0, 0, 0);
            acc[1][1] = __builtin_amdgcn_mfma_f32_16x16x32_bf16(a1, b1, acc[1][1], 0, 0, 0);
        }

#pragma unroll
        for (int m = 0; m < 2; ++m)
#pragma unroll
            for (int n = 0; n < 2; ++n)
#pragma unroll
                for (int r = 0; r < 4; ++r) {
                    int row = row0 + wr + m * 16 + fq * 4 + r;
                    int col = col0 + wc + n * 16 + fr;
                    out[(size_t)row * NB + col] = acc[m][n][r];
                }
    }
}

extern "C" void kernel_launch(void* const* d_in, const int* in_sizes, int n_in,
                              void* d_out, int out_size, void* d_ws, size_t ws_size,
                              hipStream_t stream) {
    const float* a = (const float*)d_in[0];
    const float* b = (const float*)d_in[1];
    const float* feats = (const float*)d_in[2];
    float* out = (float*)d_out;
    __hip_bfloat16* P = (__hip_bfloat16*)d_ws;                     // 512 KB
    __hip_bfloat16* M = P + (size_t)NA * KF;                       // 512 KB

    void* args[] = {(void*)&a, (void*)&b, (void*)&feats,
                    (void*)&P, (void*)&M, (void*)&out};
    hipLaunchCooperativeKernel((const void*)fused_kernel, dim3(GRID), dim3(256),
                               args, 0, stream);
}

// Round 10
// 24.451 us; speedup vs baseline: 2.0479x; 2.0479x over previous
//
#include <hip/hip_runtime.h>
#include <hip/hip_bf16.h>

typedef __attribute__((ext_vector_type(4))) float f32x4;
typedef __attribute__((ext_vector_type(4))) double f64x4;
typedef __attribute__((ext_vector_type(8))) short short8;

#define NA 1024
#define NB 1024
#define KF 256
#define DIM 128
#define GRID 256

// Fused, NO grid barrier: producer/consumer via per-64-row-group flags.
// All cross-block data (P, M, flags) moves through relaxed AGENT-scope atomics
// -> plain sc1 loads/stores at the shared-L3 coherent point; ZERO cache-wide
// writebacks/invalidates (R7/R8's 20-35us cost). Grid=256=1 block/CU, all
// co-resident -> flag spin cannot deadlock.
// Phase A: block bb projects concat rows [rb*32,+32) x fk cols [cb*64,+64)
//          (rb=bb>>2, cb=bb&3) via f64 MFMA (probe-decoded D layout), stores
//          P/M with sc1, then bumps flags[rb>>1] (8 producers per group).
// Phase B: block bb computes out tile (bb>>4, bb&15); spins on flag[bb>>4]
//          (P rows) and flag[16+(bb&15)] (M rows), stages via sc1 8B loads,
//          bf16 MFMA.

union SharedU {
    struct { float Xs[32][132]; float Fs[64][132]; } pa;   // 50.7 KB
    struct { short LA[64][264]; short LB[64][264]; } pb;   // 67.6 KB
};

__global__ __launch_bounds__(256) void fused_kernel(
    const float* __restrict__ a, const float* __restrict__ b,
    const float* __restrict__ feats,
    __hip_bfloat16* __restrict__ P, __hip_bfloat16* __restrict__ M,
    unsigned int* __restrict__ flags,
    float* __restrict__ out)
{
    __shared__ SharedU sh;
    const int t = threadIdx.x;
    const int bb = blockIdx.x;

    // ================= Phase A: fk = X @ feats^T -> P(relu), M(mask<=0) =========
    {
        const int rb = bb >> 2;            // 0..63: 32-row group of concat [a;b]
        const int cb = bb & 3;             // 0..3 : 64-col group of fk
        const int row0 = rb * 32;
        const int col0 = cb * 64;
        const bool isA = row0 < NA;
        const float* __restrict__ src = isA ? a : b;
        const int r0 = isA ? row0 : row0 - NA;

        // stage X: 32 rows x 32 f32x4 chunks = 1024, 4/thread (coalesced)
#pragma unroll
        for (int i = 0; i < 4; ++i) {
            int idx = t + i * 256;
            int r = idx >> 5, c4 = idx & 31;
            *(f32x4*)&sh.pa.Xs[r][c4 * 4] =
                *(const f32x4*)(src + (size_t)(r0 + r) * DIM + c4 * 4);
        }
        // stage F: 64 rows x 32 chunks = 2048, 8/thread
#pragma unroll
        for (int i = 0; i < 8; ++i) {
            int idx = t + i * 256;
            int r = idx >> 5, c4 = idx & 31;
            *(f32x4*)&sh.pa.Fs[r][c4 * 4] =
                *(const f32x4*)(feats + (size_t)(col0 + r) * DIM + c4 * 4);
        }
        __syncthreads();

        const int l = t & 63, w = t >> 6;
        const int fr = l & 15, fq = l >> 4;

        // layout probe: probe[r] = 4*m + 256*n for this lane's acc slot r
        f64x4 probe = {0.0, 0.0, 0.0, 0.0};
        probe = __builtin_amdgcn_mfma_f64_16x16x4f64((double)fr, 1.0, probe, 0, 0, 0);
        probe = __builtin_amdgcn_mfma_f64_16x16x4f64(1.0, 64.0 * (double)fr, probe, 0, 0, 0);

        // wave w: rows [16*(w&1), +16), cols [32*(w>>1), +32) as 2 16-col tiles
        const int wrow = (w & 1) * 16;
        const int wcol = (w >> 1) * 32;
        const float* __restrict__ xr  = &sh.pa.Xs[wrow + fr][fq];
        const float* __restrict__ fp0 = &sh.pa.Fs[wcol + fr][fq];
        const float* __restrict__ fp1 = &sh.pa.Fs[wcol + 16 + fr][fq];

        f64x4 acc[2][2] = {{{0.,0.,0.,0.},{0.,0.,0.,0.}},{{0.,0.,0.,0.},{0.,0.,0.,0.}}};
#pragma unroll
        for (int s = 0; s < 32; s += 2) {
            double x0 = (double)xr[s * 4],     x1 = (double)xr[s * 4 + 4];
            double f00 = (double)fp0[s * 4],   f01 = (double)fp0[s * 4 + 4];
            double f10 = (double)fp1[s * 4],   f11 = (double)fp1[s * 4 + 4];
            acc[0][0] = __builtin_amdgcn_mfma_f64_16x16x4f64(x0, f00, acc[0][0], 0, 0, 0);
            acc[1][0] = __builtin_amdgcn_mfma_f64_16x16x4f64(x0, f10, acc[1][0], 0, 0, 0);
            acc[0][1] = __builtin_amdgcn_mfma_f64_16x16x4f64(x1, f01, acc[0][1], 0, 0, 0);
            acc[1][1] = __builtin_amdgcn_mfma_f64_16x16x4f64(x1, f11, acc[1][1], 0, 0, 0);
        }

        // epilogue: sc1 element stores (relaxed agent atomics -> no cache ops)
#pragma unroll
        for (int tt = 0; tt < 2; ++tt) {
#pragma unroll
            for (int r = 0; r < 4; ++r) {
                int code = (int)probe[r];
                int m = (code >> 2) & 15;
                int n = code >> 8;
                double v = acc[tt][0][r] + acc[tt][1][r];
                size_t off = (size_t)(r0 + wrow + m) * KF + col0 + wcol + tt * 16 + n;
                float vr;
                unsigned short* dst;
                if (isA) {
                    vr = (v > 0.0) ? (float)v : 0.0f;
                    dst = (unsigned short*)P + off;
                } else {
                    vr = (v <= 0.0) ? 1.0f : 0.0f;
                    dst = (unsigned short*)M + off;
                }
                __hip_bfloat16 h = __float2bfloat16(vr);
                __hip_atomic_store(dst, *(unsigned short*)&h,
                                   __ATOMIC_RELAXED, __HIP_MEMORY_SCOPE_AGENT);
            }
        }

        // publish: all waves' stores complete -> one flag bump per block
        asm volatile("s_waitcnt vmcnt(0)" ::: "memory");
        __syncthreads();
        if (t == 0) {
            __hip_atomic_fetch_add(&flags[rb >> 1], 1u,
                                   __ATOMIC_RELAXED, __HIP_MEMORY_SCOPE_AGENT);
        }
    }

    // ================= Phase B: out = P @ M^T ===================================
    {
        const int row0 = (bb >> 4) * 64;
        const int col0 = (bb & 15) * 64;
        const int ga = bb >> 4;            // P rows group (a-rows)
        const int gb = 16 + (bb & 15);     // M rows group (b-rows)

        // wait for the 8 producers of each needed group (relaxed polls, no
        // cache ops; all 256 blocks co-resident -> no deadlock)
        if (t == 0) {
            while (__hip_atomic_load(&flags[ga], __ATOMIC_RELAXED,
                                     __HIP_MEMORY_SCOPE_AGENT) < 8u ||
                   __hip_atomic_load(&flags[gb], __ATOMIC_RELAXED,
                                     __HIP_MEMORY_SCOPE_AGENT) < 8u) {
                __builtin_amdgcn_s_sleep(2);
            }
        }
        __syncthreads();   // LDS reuse safety + orders staging after the spin

        const unsigned long long* P8 = (const unsigned long long*)P;
        const unsigned long long* M8 = (const unsigned long long*)M;

        // stage via sc1 8B loads (bypass stale local L2, read L3 coherent point)
#pragma unroll
        for (int i = 0; i < 8; ++i) {
            int c = t + i * 256;
            int row = c >> 5;
            int c8 = (c & 31) << 3;                        // element offset
            size_t ep = ((size_t)(row0 + row) * KF + c8) >> 2;   // u64 index
            size_t em = ((size_t)(col0 + row) * KF + c8) >> 2;
            unsigned long long p0 = __hip_atomic_load(P8 + ep,     __ATOMIC_RELAXED, __HIP_MEMORY_SCOPE_AGENT);
            unsigned long long p1 = __hip_atomic_load(P8 + ep + 1, __ATOMIC_RELAXED, __HIP_MEMORY_SCOPE_AGENT);
            unsigned long long m0 = __hip_atomic_load(M8 + em,     __ATOMIC_RELAXED, __HIP_MEMORY_SCOPE_AGENT);
            unsigned long long m1 = __hip_atomic_load(M8 + em + 1, __ATOMIC_RELAXED, __HIP_MEMORY_SCOPE_AGENT);
            *(unsigned long long*)&sh.pb.LA[row][c8]     = p0;
            *(unsigned long long*)&sh.pb.LA[row][c8 + 4] = p1;
            *(unsigned long long*)&sh.pb.LB[row][c8]     = m0;
            *(unsigned long long*)&sh.pb.LB[row][c8 + 4] = m1;
        }
        __syncthreads();

        const int lane = t & 63;
        const int wid = t >> 6;
        const int wr = (wid >> 1) * 32;
        const int wc = (wid & 1) * 32;
        const int fr = lane & 15;
        const int fq = lane >> 4;

        f32x4 acc[2][2];
#pragma unroll
        for (int m = 0; m < 2; ++m)
#pragma unroll
            for (int n = 0; n < 2; ++n)
                acc[m][n] = (f32x4){0.f, 0.f, 0.f, 0.f};

#pragma unroll
        for (int kk = 0; kk < KF / 32; ++kk) {
            const int kb = kk * 32 + fq * 8;
            short8 a0 = *(const short8*)&sh.pb.LA[wr + fr][kb];
            short8 a1 = *(const short8*)&sh.pb.LA[wr + 16 + fr][kb];
            short8 b0 = *(const short8*)&sh.pb.LB[wc + fr][kb];
            short8 b1 = *(const short8*)&sh.pb.LB[wc + 16 + fr][kb];
            acc[0][0] = __builtin_amdgcn_mfma_f32_16x16x32_bf16(a0, b0, acc[0][0], 0, 0, 0);
            acc[0][1] = __builtin_amdgcn_mfma_f32_16x16x32_bf16(a0, b1, acc[0][1], 0, 0, 0);
            acc[1][0] = __builtin_amdgcn_mfma_f32_16x16x32_bf16(a1, b0, acc[1][0], 0, 0, 0);
            acc[1][1] = __builtin_amdgcn_mfma_f32_16x16x32_bf16(a1, b1, acc[1][1], 0, 0, 0);
        }

#pragma unroll
        for (int m = 0; m < 2; ++m)
#pragma unroll
            for (int n = 0; n < 2; ++n)
#pragma unroll
                for (int r = 0; r < 4; ++r) {
                    int row = row0 + wr + m * 16 + fq * 4 + r;
                    int col = col0 + wc + n * 16 + fr;
                    out[(size_t)row * NB + col] = acc[m][n][r];
                }
    }
}

extern "C" void kernel_launch(void* const* d_in, const int* in_sizes, int n_in,
                              void* d_out, int out_size, void* d_ws, size_t ws_size,
                              hipStream_t stream) {
    const float* a = (const float*)d_in[0];
    const float* b = (const float*)d_in[1];
    const float* feats = (const float*)d_in[2];
    float* out = (float*)d_out;
    __hip_bfloat16* P = (__hip_bfloat16*)d_ws;                       // 512 KB
    __hip_bfloat16* M = P + (size_t)NA * KF;                         // 512 KB
    unsigned int* flags = (unsigned int*)((char*)d_ws + (1u << 20)); // 32 u32

    hipMemsetAsync(flags, 0, 32 * sizeof(unsigned int), stream);
    fused_kernel<<<dim3(GRID), dim3(256), 0, stream>>>(a, b, feats, P, M, flags, out);
}

// Round 11
// 14.401 us; speedup vs baseline: 3.4771x; 1.6979x over previous
//
#include <hip/hip_runtime.h>
#include <hip/hip_bf16.h>

typedef __attribute__((ext_vector_type(4))) float f32x4;
typedef __attribute__((ext_vector_type(4))) double f64x4;
typedef __attribute__((ext_vector_type(4))) short short4v;
typedef __attribute__((ext_vector_type(8))) short short8;

#define NA 1024
#define NB 1024
#define KF 256
#define DIM 128

// ---------------- Phase 1: fk = X @ feats^T -> P (relu, bf16), M (mask<=0, bf16) ----
// Asymmetric precision (R11):
//  * B-rows (mask side): f64 MFMA + probe-decoded D layout — signs must match the
//    f32 numpy reference essentially exactly (a flipped mask injects relu(a_fk)~40
//    into a whole output column; threshold is 23.84).
//  * A-rows (P side): 3-product bf16-split MFMA (hi*hi + hi*lo + lo*hi, f32 acc).
//    |err| ~ 3e-4 absolute, invisible under P's own bf16 storage rounding (2e-2).
//    Halves the f64 MFMA work (the proj kernel's critical path).
// Grid = 512: blocks 0..255 A-side, 256..511 B-side (round-robin dispatch pairs
// one of each per CU). Per block: 64 rows x 16 fk-cols.

union ProjShared {
    struct {  // A-side: bf16 hi/lo staging (rows padded to 136 shorts = 272B, 16B-mult)
        short XsH[64][136]; short XsL[64][136];
        short FsH[16][136]; short FsL[16][136];
    } A;                                            // 43.5 KB
    struct {  // B-side: f32 staging for f64 MFMA (R6-verified)
        float Xs[64][132]; float Fs[16][132];
    } B;                                            // 42.2 KB
};

__global__ __launch_bounds__(256) void proj_kernel(
    const float* __restrict__ a, const float* __restrict__ b,
    const float* __restrict__ feats,
    __hip_bfloat16* __restrict__ P, __hip_bfloat16* __restrict__ M)
{
    __shared__ ProjShared sh;
    const int t = threadIdx.x;
    const bool isA = blockIdx.x < 256;
    const int idx_blk = isA ? blockIdx.x : (blockIdx.x - 256);
    const int rowBlk = idx_blk >> 4;     // 0..15 : 64-row group
    const int colBlk = idx_blk & 15;     // 0..15 : 16-col group
    const int r0 = rowBlk * 64;
    const int col0 = colBlk * 16;

    const int l = t & 63, w = t >> 6;
    const int fr = l & 15, fq = l >> 4;

    if (isA) {
        // ---- stage a -> hi/lo bf16: 64 rows x 32 f32x4 chunks, 8/thread ----
#pragma unroll
        for (int i = 0; i < 8; ++i) {
            int idx = t + i * 256;
            int r = idx >> 5, c4 = idx & 31;
            f32x4 v = *(const f32x4*)(a + (size_t)(r0 + r) * DIM + c4 * 4);
            short4v hi4, lo4;
#pragma unroll
            for (int j = 0; j < 4; ++j) {
                __hip_bfloat16 h = __float2bfloat16(v[j]);
                float hf = __bfloat162float(h);
                __hip_bfloat16 lo = __float2bfloat16(v[j] - hf);
                hi4[j] = *(short*)&h;
                lo4[j] = *(short*)&lo;
            }
            *(short4v*)&sh.A.XsH[r][c4 * 4] = hi4;
            *(short4v*)&sh.A.XsL[r][c4 * 4] = lo4;
        }
        // ---- stage feats slice: 16 rows x 32 chunks, 2/thread ----
#pragma unroll
        for (int i = 0; i < 2; ++i) {
            int idx = t + i * 256;
            int r = idx >> 5, c4 = idx & 31;
            f32x4 v = *(const f32x4*)(feats + (size_t)(col0 + r) * DIM + c4 * 4);
            short4v hi4, lo4;
#pragma unroll
            for (int j = 0; j < 4; ++j) {
                __hip_bfloat16 h = __float2bfloat16(v[j]);
                float hf = __bfloat162float(h);
                __hip_bfloat16 lo = __float2bfloat16(v[j] - hf);
                hi4[j] = *(short*)&h;
                lo4[j] = *(short*)&lo;
            }
            *(short4v*)&sh.A.FsH[r][c4 * 4] = hi4;
            *(short4v*)&sh.A.FsL[r][c4 * 4] = lo4;
        }
        __syncthreads();

        // wave w: rows [w*16, +16), all 16 cols; K=128 in 4 chunks x 3 products
        f32x4 acc = (f32x4){0.f, 0.f, 0.f, 0.f};
#pragma unroll
        for (int kk = 0; kk < 4; ++kk) {
            const int kb = kk * 32 + fq * 8;
            short8 ah = *(const short8*)&sh.A.XsH[w * 16 + fr][kb];
            short8 al = *(const short8*)&sh.A.XsL[w * 16 + fr][kb];
            short8 fh = *(const short8*)&sh.A.FsH[fr][kb];
            short8 fl = *(const short8*)&sh.A.FsL[fr][kb];
            acc = __builtin_amdgcn_mfma_f32_16x16x32_bf16(ah, fh, acc, 0, 0, 0);
            acc = __builtin_amdgcn_mfma_f32_16x16x32_bf16(ah, fl, acc, 0, 0, 0);
            acc = __builtin_amdgcn_mfma_f32_16x16x32_bf16(al, fh, acc, 0, 0, 0);
        }

        // verified bf16 D layout (m89): col = l&15, row = (l>>4)*4 + reg
#pragma unroll
        for (int r = 0; r < 4; ++r) {
            float v = (acc[r] > 0.0f) ? acc[r] : 0.0f;
            P[(size_t)(r0 + w * 16 + fq * 4 + r) * KF + col0 + fr] =
                __float2bfloat16(v);
        }
    } else {
        // ---- B-side: R6-verified f64 MFMA path ----
#pragma unroll
        for (int i = 0; i < 8; ++i) {
            int idx = t + i * 256;
            int r = idx >> 5, c4 = idx & 31;
            *(f32x4*)&sh.B.Xs[r][c4 * 4] =
                *(const f32x4*)(b + (size_t)(r0 + r) * DIM + c4 * 4);
        }
#pragma unroll
        for (int i = 0; i < 2; ++i) {
            int idx = t + i * 256;
            int r = idx >> 5, c4 = idx & 31;
            *(f32x4*)&sh.B.Fs[r][c4 * 4] =
                *(const f32x4*)(feats + (size_t)(col0 + r) * DIM + c4 * 4);
        }
        __syncthreads();

        // layout probe: probe[r] = 4*m + 256*n for this lane's acc slot r
        f64x4 probe = {0.0, 0.0, 0.0, 0.0};
        probe = __builtin_amdgcn_mfma_f64_16x16x4f64((double)fr, 1.0, probe, 0, 0, 0);
        probe = __builtin_amdgcn_mfma_f64_16x16x4f64(1.0, 64.0 * (double)fr, probe, 0, 0, 0);

        const float* __restrict__ xr = &sh.B.Xs[w * 16 + fr][fq];
        const float* __restrict__ fp = &sh.B.Fs[fr][fq];

        f64x4 acc0 = {0.0, 0.0, 0.0, 0.0};
        f64x4 acc1 = {0.0, 0.0, 0.0, 0.0};
#pragma unroll
        for (int s = 0; s < 32; s += 2) {
            double x0 = (double)xr[s * 4], f0 = (double)fp[s * 4];
            acc0 = __builtin_amdgcn_mfma_f64_16x16x4f64(x0, f0, acc0, 0, 0, 0);
            double x1 = (double)xr[s * 4 + 4], f1 = (double)fp[s * 4 + 4];
            acc1 = __builtin_amdgcn_mfma_f64_16x16x4f64(x1, f1, acc1, 0, 0, 0);
        }

#pragma unroll
        for (int r = 0; r < 4; ++r) {
            int code = (int)probe[r];
            int m = (code >> 2) & 15;
            int n = code >> 8;
            double v = acc0[r] + acc1[r];
            float vr = (v <= 0.0) ? 1.0f : 0.0f;
            M[(size_t)(r0 + w * 16 + m) * KF + col0 + n] = __float2bfloat16(vr);
        }
    }
}

// ---------------- Phase 2: out = P @ M^T, bf16 MFMA, f32 accumulate (unchanged) ------
__global__ __launch_bounds__(256) void gemm_kernel(
    const __hip_bfloat16* __restrict__ P, const __hip_bfloat16* __restrict__ M,
    float* __restrict__ out)
{
    __shared__ short LA[64][264];
    __shared__ short LB[64][264];
    const int t = threadIdx.x;
    const int row0 = blockIdx.y * 64;
    const int col0 = blockIdx.x * 64;
    const short* Pa = (const short*)P;
    const short* Mb = (const short*)M;

#pragma unroll
    for (int i = 0; i < 8; ++i) {
        int c = t + i * 256;
        int row = c >> 5;
        int c8 = (c & 31) << 3;
        *(short8*)&LA[row][c8] = *(const short8*)(Pa + (size_t)(row0 + row) * KF + c8);
        *(short8*)&LB[row][c8] = *(const short8*)(Mb + (size_t)(col0 + row) * KF + c8);
    }
    __syncthreads();

    const int lane = t & 63;
    const int wid = t >> 6;
    const int wr = (wid >> 1) * 32;
    const int wc = (wid & 1) * 32;
    const int fr = lane & 15;
    const int fq = lane >> 4;

    f32x4 acc[2][2];
#pragma unroll
    for (int m = 0; m < 2; ++m)
#pragma unroll
        for (int n = 0; n < 2; ++n)
            acc[m][n] = (f32x4){0.f, 0.f, 0.f, 0.f};

#pragma unroll
    for (int kk = 0; kk < KF / 32; ++kk) {
        const int kb = kk * 32 + fq * 8;
        short8 a0 = *(const short8*)&LA[wr + fr][kb];
        short8 a1 = *(const short8*)&LA[wr + 16 + fr][kb];
        short8 b0 = *(const short8*)&LB[wc + fr][kb];
        short8 b1 = *(const short8*)&LB[wc + 16 + fr][kb];
        acc[0][0] = __builtin_amdgcn_mfma_f32_16x16x32_bf16(a0, b0, acc[0][0], 0, 0, 0);
        acc[0][1] = __builtin_amdgcn_mfma_f32_16x16x32_bf16(a0, b1, acc[0][1], 0, 0, 0);
        acc[1][0] = __builtin_amdgcn_mfma_f32_16x16x32_bf16(a1, b0, acc[1][0], 0, 0, 0);
        acc[1][1] = __builtin_amdgcn_mfma_f32_16x16x32_bf16(a1, b1, acc[1][1], 0, 0, 0);
    }

#pragma unroll
    for (int m = 0; m < 2; ++m)
#pragma unroll
        for (int n = 0; n < 2; ++n)
#pragma unroll
            for (int r = 0; r < 4; ++r) {
                int row = row0 + wr + m * 16 + fq * 4 + r;
                int col = col0 + wc + n * 16 + fr;
                out[(size_t)row * NB + col] = acc[m][n][r];
            }
}

extern "C" void kernel_launch(void* const* d_in, const int* in_sizes, int n_in,
                              void* d_out, int out_size, void* d_ws, size_t ws_size,
                              hipStream_t stream) {
    const float* a = (const float*)d_in[0];
    const float* b = (const float*)d_in[1];
    const float* feats = (const float*)d_in[2];
    float* out = (float*)d_out;
    __hip_bfloat16* P = (__hip_bfloat16*)d_ws;
    __hip_bfloat16* M = P + (size_t)NA * KF;

    proj_kernel<<<dim3(512), dim3(256), 0, stream>>>(a, b, feats, P, M);
    gemm_kernel<<<dim3(NB / 64, NA / 64), dim3(256), 0, stream>>>(P, M, out);
}